// Round 1
// baseline (2001.866 us; speedup 1.0000x reference)
//
#include <hip/hip_runtime.h>
#include <hip/hip_bf16.h>

// Problem constants
#define BB 16
#define NN 8192
#define SS 1024
#define GG 32
// sortable(1.0f) = 0x3F800000 ^ 0x80000000
#define SORT_R2 0xBF800000u

__device__ __forceinline__ unsigned sortable(float f) {
    unsigned u = __float_as_uint(f);
    return u ^ ((unsigned)(((int)u) >> 31) | 0x80000000u);
}

// ---------------------------------------------------------------------------
// Kernel 1: pack pts4[b][n] = {x, y, z, (x*x+y*y)+z*z}  (rn ops, no contraction)
// ---------------------------------------------------------------------------
__global__ __launch_bounds__(256) void k_pts(const float* __restrict__ coor,
                                             float4* __restrict__ pts4) {
    int i = blockIdx.x * 256 + threadIdx.x;   // 0 .. B*N-1
    int b = i >> 13, n = i & (NN - 1);
    const float* cb = coor + (long)b * 3 * NN;
    float x = cb[n], y = cb[NN + n], z = cb[2 * NN + n];
    float pn = __fadd_rn(__fadd_rn(__fmul_rn(x, x), __fmul_rn(y, y)), __fmul_rn(z, z));
    pts4[i] = make_float4(x, y, z, pn);
}

// ---------------------------------------------------------------------------
// Kernel 2: transpose fea (B,64,N) -> feaT (B,N,64)
// ---------------------------------------------------------------------------
__global__ __launch_bounds__(256) void k_tr(const float* __restrict__ fea,
                                            float* __restrict__ feaT) {
    __shared__ float tile[64][65];
    int b = blockIdx.y, n0 = blockIdx.x * 64;
    int t = threadIdx.x;
    int nl = t & 63, cb = t >> 6;
#pragma unroll
    for (int i = 0; i < 16; i++) {
        int c = cb * 16 + i;
        tile[nl][c] = fea[((long)b * 64 + c) * NN + n0 + nl];
    }
    __syncthreads();
    int cl = t & 63, nb = t >> 6;
#pragma unroll
    for (int i = 0; i < 16; i++) {
        int n = nb * 16 + i;
        feaT[((long)b * NN + n0 + n) * 64 + cl] = tile[n][cl];
    }
}

// ---------------------------------------------------------------------------
// Kernel 3: farthest point sampling. One block (512 thr) per batch.
// Bit-exact distance chain: (dx*dx + dy*dy) + dz*dz, all rn (no FMA).
// Argmax tie-break = first (lowest) index via packed u64 max.
// ---------------------------------------------------------------------------
__global__ __launch_bounds__(512) void k_fps(const float4* __restrict__ pts4,
                                             float4* __restrict__ qpts,
                                             float* __restrict__ out) {
    __shared__ float xs[NN], ys[NN], zs[NN];
    __shared__ unsigned long long red[2][8];
    int b = blockIdx.x;
    int t = threadIdx.x;
    const float4* P = pts4 + (long)b * NN;

    float px[16], py[16], pz[16], dist[16];
#pragma unroll
    for (int j = 0; j < 16; j++) {
        int p = t + j * 512;
        float4 v = P[p];
        px[j] = v.x; py[j] = v.y; pz[j] = v.z;
        dist[j] = 1e10f;
        xs[p] = v.x; ys[p] = v.y; zs[p] = v.z;
    }
    __syncthreads();

    int cur = 0;
    for (int s = 0; s < SS; s++) {
        float cx = xs[cur], cy = ys[cur], cz = zs[cur];
        if (t == 0) {
            // new_coor output (B,3,S) + query point (x,y,z,qn) for KNN
            out[(long)b * 3 * SS + s]          = cx;
            out[(long)b * 3 * SS + SS + s]     = cy;
            out[(long)b * 3 * SS + 2 * SS + s] = cz;
            float qn = __fadd_rn(__fadd_rn(__fmul_rn(cx, cx), __fmul_rn(cy, cy)),
                                 __fmul_rn(cz, cz));
            qpts[(long)b * SS + s] = make_float4(cx, cy, cz, qn);
        }
        float bv = -1.0f;
        int bj = 0;
#pragma unroll
        for (int j = 0; j < 16; j++) {
            float dx = __fsub_rn(px[j], cx);
            float dy = __fsub_rn(py[j], cy);
            float dz = __fsub_rn(pz[j], cz);
            float d = __fadd_rn(__fadd_rn(__fmul_rn(dx, dx), __fmul_rn(dy, dy)),
                                __fmul_rn(dz, dz));
            float nd = fminf(dist[j], d);
            dist[j] = nd;
            bool c = nd > bv;          // strict: keeps earliest j on ties
            bv = c ? nd : bv;
            bj = c ? j : bj;
        }
        int bp = t + bj * 512;
        // dist >= 0 so float bits are monotonic; (8191-idx) => max picks min idx on ties
        unsigned long long key =
            ((unsigned long long)__float_as_uint(bv) << 32) | (unsigned)(8191 - bp);
#pragma unroll
        for (int m = 1; m < 64; m <<= 1) {
            unsigned long long o = __shfl_xor(key, m, 64);
            key = (o > key) ? o : key;
        }
        int wid = t >> 6;
        int par = s & 1;
        if ((t & 63) == 0) red[par][wid] = key;
        __syncthreads();
        unsigned long long best = red[par][0];
#pragma unroll
        for (int w = 1; w < 8; w++) {
            unsigned long long o = red[par][w];
            best = (o > best) ? o : best;
        }
        cur = 8191 - (int)(best & 0xFFFFFFFFu);
    }
}

// ---------------------------------------------------------------------------
// Kernel 4: exact 32-NN per query (one wave per query), reference formula
// d = (qn - 2*dot) + pn; stable tie-break by index (matches lax.top_k);
// radius filter d > 1.0 -> replace with nearest index.
// ---------------------------------------------------------------------------
#define SKEW(p) ((p) + ((p) >> 5))
__global__ __launch_bounds__(64) void k_knn(const float4* __restrict__ pts4,
                                            const float4* __restrict__ qpts,
                                            int* __restrict__ gidx) {
    __shared__ unsigned dk[NN + NN / 32];   // 8448
    int Q = blockIdx.x;                      // b*1024 + s
    int b = Q >> 10;
    int l = threadIdx.x;
    float4 q = qpts[Q];
    const float4* P = pts4 + (long)b * NN;

    unsigned bmin = 0xFFFFFFFFu;
    int bpos = 0;
    for (int j = 0; j < 128; j++) {
        int p = j * 64 + l;
        float4 v = P[p];
        float dot = __fadd_rn(__fadd_rn(__fmul_rn(q.x, v.x), __fmul_rn(q.y, v.y)),
                              __fmul_rn(q.z, v.z));
        float d = __fadd_rn(__fsub_rn(q.w, __fmul_rn(2.0f, dot)), v.w);
        unsigned u = sortable(d);
        dk[SKEW(p)] = u;
        if (u < bmin) { bmin = u; bpos = p; }   // ascending p -> earliest index on tie
    }
    __syncthreads();

    int pos0 = 0;
    for (int k = 0; k < GG; k++) {
        unsigned long long key = ((unsigned long long)bmin << 32) | (unsigned)bpos;
#pragma unroll
        for (int m = 1; m < 64; m <<= 1) {
            unsigned long long o = __shfl_xor(key, m, 64);
            key = (o < key) ? o : key;
        }
        int kpos = (int)(key & 0xFFFFFFFFu);
        unsigned kval = (unsigned)(key >> 32);
        if (k == 0) pos0 = kpos;
        if (l == 0) gidx[(long)Q * GG + k] = (kval > SORT_R2) ? pos0 : kpos;
        int owner = kpos & 63;
        if (l == owner) dk[SKEW(kpos)] = 0xFFFFFFFFu;   // invalidate popped slot
        __syncthreads();
        // cooperative rescan of owner's column (its 128 points)
        int p1 = l * 64 + owner;
        int p2 = (l + 64) * 64 + owner;
        unsigned v1 = dk[SKEW(p1)], v2 = dk[SKEW(p2)];
        unsigned long long c1 = ((unsigned long long)v1 << 32) | (unsigned)p1;
        unsigned long long c2 = ((unsigned long long)v2 << 32) | (unsigned)p2;
        unsigned long long cand = (c2 < c1) ? c2 : c1;
#pragma unroll
        for (int m = 1; m < 64; m <<= 1) {
            unsigned long long o = __shfl_xor(cand, m, 64);
            cand = (o < cand) ? o : cand;
        }
        if (l == owner) { bmin = (unsigned)(cand >> 32); bpos = (int)(cand & 0xFFFFFFFFu); }
        __syncthreads();
    }
}

// ---------------------------------------------------------------------------
// Kernel 5: gather + 1x1 conv (W: 128x67) + relu + max over group.
// Block = 256 thr = 4 waves = 4 queries; W rows live in registers.
// ---------------------------------------------------------------------------
__global__ __launch_bounds__(256, 2) void k_mlp(const float4* __restrict__ pts4,
                                                const float* __restrict__ feaT,
                                                const float4* __restrict__ qpts,
                                                const int* __restrict__ gidx,
                                                const float* __restrict__ W,
                                                float* __restrict__ out) {
    __shared__ float sm[8704];   // max(8576 W floats, 4*32*68 grouped floats)
    int t = threadIdx.x, l = t & 63, w = t >> 6;

    for (int i = t; i < 8576; i += 256) sm[i] = W[i];
    __syncthreads();
    float wa[68], wb[68];
#pragma unroll
    for (int c = 0; c < 68; c++) {
        wa[c] = (c < 67) ? sm[l * 67 + c] : 0.f;
        wb[c] = (c < 67) ? sm[(l + 64) * 67 + c] : 0.f;
    }
    __syncthreads();   // done reading W region before reuse

    int Q = blockIdx.x * 4 + w;
    int b = Q >> 10, s = Q & 1023;
    float4 q = qpts[Q];
    const int* gi = gidx + (long)Q * GG;
    int base = w * 2176;   // 32*68 per wave

    if (l < 32) {
        int idx = gi[l];
        float4 p = pts4[(long)b * NN + idx];
        float4 rc = make_float4(__fsub_rn(p.x, q.x), __fsub_rn(p.y, q.y),
                                __fsub_rn(p.z, q.z), 0.f);
        *(float4*)&sm[base + l * 68 + 64] = rc;
    }
    {
        int g = l >> 1, half = l & 1;
        int idx = gi[g];
        const float4* f4 = (const float4*)(feaT + ((long)b * NN + idx) * 64);
#pragma unroll
        for (int k = 0; k < 8; k++) {
            *(float4*)&sm[base + g * 68 + half * 32 + k * 4] = f4[half * 8 + k];
        }
    }
    __syncthreads();

    float m0 = -1e30f, m1 = -1e30f;
#pragma unroll 2
    for (int g = 0; g < GG; g++) {
        float a0 = 0.f, a1 = 0.f;
#pragma unroll
        for (int c4 = 0; c4 < 17; c4++) {
            float4 gv = *(float4*)&sm[base + g * 68 + c4 * 4];
            a0 = fmaf(gv.x, wa[4 * c4 + 0], a0);
            a0 = fmaf(gv.y, wa[4 * c4 + 1], a0);
            a0 = fmaf(gv.z, wa[4 * c4 + 2], a0);
            a0 = fmaf(gv.w, wa[4 * c4 + 3], a0);
            a1 = fmaf(gv.x, wb[4 * c4 + 0], a1);
            a1 = fmaf(gv.y, wb[4 * c4 + 1], a1);
            a1 = fmaf(gv.z, wb[4 * c4 + 2], a1);
            a1 = fmaf(gv.w, wb[4 * c4 + 3], a1);
        }
        m0 = fmaxf(m0, a0);
        m1 = fmaxf(m1, a1);
    }
    // outputs: (B,3,S) then (B,128,S); relu(max) == max(relu)
    out[49152 + ((long)b * 128 + l) * SS + s]      = fmaxf(m0, 0.f);
    out[49152 + ((long)b * 128 + l + 64) * SS + s] = fmaxf(m1, 0.f);
}

// ---------------------------------------------------------------------------
extern "C" void kernel_launch(void* const* d_in, const int* in_sizes, int n_in,
                              void* d_out, int out_size, void* d_ws, size_t ws_size,
                              hipStream_t stream) {
    const float* coor = (const float*)d_in[0];   // (16,3,8192)
    const float* fea  = (const float*)d_in[1];   // (16,64,8192)
    const float* Wm   = (const float*)d_in[2];   // (128,67)
    float* out = (float*)d_out;

    char* ws = (char*)d_ws;
    float4* pts4 = (float4*)ws;                               //  2 MB
    float*  feaT = (float*)(ws + 2097152);                    // 32 MB
    float4* qpts = (float4*)(ws + 2097152 + 33554432);        // 256 KB
    int*    gidx = (int*)(ws + 2097152 + 33554432 + 262144);  //  2 MB

    k_pts<<<(BB * NN) / 256, 256, 0, stream>>>(coor, pts4);
    k_tr<<<dim3(NN / 64, BB), 256, 0, stream>>>(fea, feaT);
    k_fps<<<BB, 512, 0, stream>>>(pts4, qpts, out);
    k_knn<<<BB * SS, 64, 0, stream>>>(pts4, qpts, gidx);
    k_mlp<<<(BB * SS) / 4, 256, 0, stream>>>(pts4, feaT, qpts, gidx, Wm, out);
}

// Round 2
// 1850.294 us; speedup vs baseline: 1.0819x; 1.0819x over previous
//
#include <hip/hip_runtime.h>
#include <hip/hip_bf16.h>

// Problem constants
#define BB 16
#define NN 8192
#define SS 1024
#define GG 32
// sortable(1.0f) = 0x3F800000 ^ 0x80000000
#define SORT_R2 0xBF800000u

__device__ __forceinline__ unsigned sortable(float f) {
    unsigned u = __float_as_uint(f);
    return u ^ ((unsigned)(((int)u) >> 31) | 0x80000000u);
}

// ---------------------------------------------------------------------------
// Kernel 1: pack pts4[b][n] = {x, y, z, (x*x+y*y)+z*z}  (rn ops, no contraction)
// ---------------------------------------------------------------------------
__global__ __launch_bounds__(256) void k_pts(const float* __restrict__ coor,
                                             float4* __restrict__ pts4) {
    int i = blockIdx.x * 256 + threadIdx.x;   // 0 .. B*N-1
    int b = i >> 13, n = i & (NN - 1);
    const float* cb = coor + (long)b * 3 * NN;
    float x = cb[n], y = cb[NN + n], z = cb[2 * NN + n];
    float pn = __fadd_rn(__fadd_rn(__fmul_rn(x, x), __fmul_rn(y, y)), __fmul_rn(z, z));
    pts4[i] = make_float4(x, y, z, pn);
}

// ---------------------------------------------------------------------------
// Kernel 2: transpose fea (B,64,N) -> feaT (B,N,64)
// ---------------------------------------------------------------------------
__global__ __launch_bounds__(256) void k_tr(const float* __restrict__ fea,
                                            float* __restrict__ feaT) {
    __shared__ float tile[64][65];
    int b = blockIdx.y, n0 = blockIdx.x * 64;
    int t = threadIdx.x;
    int nl = t & 63, cb = t >> 6;
#pragma unroll
    for (int i = 0; i < 16; i++) {
        int c = cb * 16 + i;
        tile[nl][c] = fea[((long)b * 64 + c) * NN + n0 + nl];
    }
    __syncthreads();
    int cl = t & 63, nb = t >> 6;
#pragma unroll
    for (int i = 0; i < 16; i++) {
        int n = nb * 16 + i;
        feaT[((long)b * NN + n0 + n) * 64 + cl] = tile[n][cl];
    }
}

// ---------------------------------------------------------------------------
// Kernel 3: farthest point sampling. One block (512 thr) per batch.
// Bit-exact distance chain: (dx*dx + dy*dy) + dz*dz, all rn (no FMA).
// Argmax tie-break = first (lowest) index via packed u64 max.
// v2: NO global stores inside the step loop (they forced a vmcnt(0) drain at
// every barrier). Chosen indices go to LDS; outputs written in an epilogue.
// Dual 8-deep argmax chains halve the serial cmp/sel dependency.
// ---------------------------------------------------------------------------
__global__ __launch_bounds__(512) void k_fps(const float4* __restrict__ pts4,
                                             float4* __restrict__ qpts,
                                             float* __restrict__ out) {
    __shared__ float xs[NN], ys[NN], zs[NN];
    __shared__ int scur[SS];
    __shared__ unsigned long long red[2][8];
    int b = blockIdx.x;
    int t = threadIdx.x;
    const float4* P = pts4 + (long)b * NN;

    float px[16], py[16], pz[16], dist[16];
#pragma unroll
    for (int j = 0; j < 16; j++) {
        int p = t + j * 512;
        float4 v = P[p];
        px[j] = v.x; py[j] = v.y; pz[j] = v.z;
        dist[j] = 1e10f;
        xs[p] = v.x; ys[p] = v.y; zs[p] = v.z;
    }
    __syncthreads();

    int cur = 0;
    for (int s = 0; s < SS; s++) {
        float cx = xs[cur], cy = ys[cur], cz = zs[cur];
        if (t == 0) scur[s] = cur;   // LDS only — no vmcnt at the barrier
        // two independent argmax chains; chain0 indices (j<8) are all smaller
        // than chain1's, so strict-> merge keeps exact lowest-index ties.
        float bv0 = -1.0f, bv1 = -1.0f;
        int bj0 = 0, bj1 = 8;
#pragma unroll
        for (int j = 0; j < 8; j++) {
            {
                float dx = __fsub_rn(px[j], cx);
                float dy = __fsub_rn(py[j], cy);
                float dz = __fsub_rn(pz[j], cz);
                float d = __fadd_rn(__fadd_rn(__fmul_rn(dx, dx), __fmul_rn(dy, dy)),
                                    __fmul_rn(dz, dz));
                float nd = fminf(dist[j], d);
                dist[j] = nd;
                bool c = nd > bv0;
                bv0 = c ? nd : bv0;
                bj0 = c ? j : bj0;
            }
            {
                int j1 = j + 8;
                float dx = __fsub_rn(px[j1], cx);
                float dy = __fsub_rn(py[j1], cy);
                float dz = __fsub_rn(pz[j1], cz);
                float d = __fadd_rn(__fadd_rn(__fmul_rn(dx, dx), __fmul_rn(dy, dy)),
                                    __fmul_rn(dz, dz));
                float nd = fminf(dist[j1], d);
                dist[j1] = nd;
                bool c = nd > bv1;
                bv1 = c ? nd : bv1;
                bj1 = c ? j1 : bj1;
            }
        }
        bool cm = bv1 > bv0;                 // tie -> chain0 (smaller index)
        float bv = cm ? bv1 : bv0;
        int bj = cm ? bj1 : bj0;
        int bp = t + bj * 512;
        // dist >= 0 so float bits are monotonic; (8191-idx) => max picks min idx on ties
        unsigned long long key =
            ((unsigned long long)__float_as_uint(bv) << 32) | (unsigned)(8191 - bp);
#pragma unroll
        for (int m = 1; m < 64; m <<= 1) {
            unsigned long long o = __shfl_xor(key, m, 64);
            key = (o > key) ? o : key;
        }
        int wid = t >> 6;
        int par = s & 1;
        if ((t & 63) == 0) red[par][wid] = key;
        __syncthreads();
        unsigned long long best = red[par][0];
#pragma unroll
        for (int w = 1; w < 8; w++) {
            unsigned long long o = red[par][w];
            best = (o > best) ? o : best;
        }
        cur = 8191 - (int)(best & 0xFFFFFFFFu);
    }
    __syncthreads();

    // epilogue: write new_coor (B,3,S) and query points from the recorded indices
#pragma unroll
    for (int s = t; s < SS; s += 512) {
        int c = scur[s];
        float cx = xs[c], cy = ys[c], cz = zs[c];
        out[(long)b * 3 * SS + s]          = cx;
        out[(long)b * 3 * SS + SS + s]     = cy;
        out[(long)b * 3 * SS + 2 * SS + s] = cz;
        float qn = __fadd_rn(__fadd_rn(__fmul_rn(cx, cx), __fmul_rn(cy, cy)),
                             __fmul_rn(cz, cz));
        qpts[(long)b * SS + s] = make_float4(cx, cy, cz, qn);
    }
}

// ---------------------------------------------------------------------------
// Kernel 4: exact 32-NN per query (one wave per query), reference formula
// d = (qn - 2*dot) + pn; stable tie-break by index (matches lax.top_k);
// radius filter d > 1.0 -> replace with nearest index.
// ---------------------------------------------------------------------------
#define SKEW(p) ((p) + ((p) >> 5))
__global__ __launch_bounds__(64) void k_knn(const float4* __restrict__ pts4,
                                            const float4* __restrict__ qpts,
                                            int* __restrict__ gidx) {
    __shared__ unsigned dk[NN + NN / 32];   // 8448
    int Q = blockIdx.x;                      // b*1024 + s
    int b = Q >> 10;
    int l = threadIdx.x;
    float4 q = qpts[Q];
    const float4* P = pts4 + (long)b * NN;

    unsigned bmin = 0xFFFFFFFFu;
    int bpos = 0;
    for (int j = 0; j < 128; j++) {
        int p = j * 64 + l;
        float4 v = P[p];
        float dot = __fadd_rn(__fadd_rn(__fmul_rn(q.x, v.x), __fmul_rn(q.y, v.y)),
                              __fmul_rn(q.z, v.z));
        float d = __fadd_rn(__fsub_rn(q.w, __fmul_rn(2.0f, dot)), v.w);
        unsigned u = sortable(d);
        dk[SKEW(p)] = u;
        if (u < bmin) { bmin = u; bpos = p; }   // ascending p -> earliest index on tie
    }
    __syncthreads();

    int pos0 = 0;
    for (int k = 0; k < GG; k++) {
        unsigned long long key = ((unsigned long long)bmin << 32) | (unsigned)bpos;
#pragma unroll
        for (int m = 1; m < 64; m <<= 1) {
            unsigned long long o = __shfl_xor(key, m, 64);
            key = (o < key) ? o : key;
        }
        int kpos = (int)(key & 0xFFFFFFFFu);
        unsigned kval = (unsigned)(key >> 32);
        if (k == 0) pos0 = kpos;
        if (l == 0) gidx[(long)Q * GG + k] = (kval > SORT_R2) ? pos0 : kpos;
        int owner = kpos & 63;
        if (l == owner) dk[SKEW(kpos)] = 0xFFFFFFFFu;   // invalidate popped slot
        __syncthreads();
        // cooperative rescan of owner's column (its 128 points)
        int p1 = l * 64 + owner;
        int p2 = (l + 64) * 64 + owner;
        unsigned v1 = dk[SKEW(p1)], v2 = dk[SKEW(p2)];
        unsigned long long c1 = ((unsigned long long)v1 << 32) | (unsigned)p1;
        unsigned long long c2 = ((unsigned long long)v2 << 32) | (unsigned)p2;
        unsigned long long cand = (c2 < c1) ? c2 : c1;
#pragma unroll
        for (int m = 1; m < 64; m <<= 1) {
            unsigned long long o = __shfl_xor(cand, m, 64);
            cand = (o < cand) ? o : cand;
        }
        if (l == owner) { bmin = (unsigned)(cand >> 32); bpos = (int)(cand & 0xFFFFFFFFu); }
        __syncthreads();
    }
}

// ---------------------------------------------------------------------------
// Kernel 5: gather + 1x1 conv (W: 128x67) + relu + max over group.
// Block = 256 thr = 4 waves = 4 queries; W rows live in registers.
// ---------------------------------------------------------------------------
__global__ __launch_bounds__(256, 2) void k_mlp(const float4* __restrict__ pts4,
                                                const float* __restrict__ feaT,
                                                const float4* __restrict__ qpts,
                                                const int* __restrict__ gidx,
                                                const float* __restrict__ W,
                                                float* __restrict__ out) {
    __shared__ float sm[8704];   // max(8576 W floats, 4*32*68 grouped floats)
    int t = threadIdx.x, l = t & 63, w = t >> 6;

    for (int i = t; i < 8576; i += 256) sm[i] = W[i];
    __syncthreads();
    float wa[68], wb[68];
#pragma unroll
    for (int c = 0; c < 68; c++) {
        wa[c] = (c < 67) ? sm[l * 67 + c] : 0.f;
        wb[c] = (c < 67) ? sm[(l + 64) * 67 + c] : 0.f;
    }
    __syncthreads();   // done reading W region before reuse

    int Q = blockIdx.x * 4 + w;
    int b = Q >> 10, s = Q & 1023;
    float4 q = qpts[Q];
    const int* gi = gidx + (long)Q * GG;
    int base = w * 2176;   // 32*68 per wave

    if (l < 32) {
        int idx = gi[l];
        float4 p = pts4[(long)b * NN + idx];
        float4 rc = make_float4(__fsub_rn(p.x, q.x), __fsub_rn(p.y, q.y),
                                __fsub_rn(p.z, q.z), 0.f);
        *(float4*)&sm[base + l * 68 + 64] = rc;
    }
    {
        int g = l >> 1, half = l & 1;
        int idx = gi[g];
        const float4* f4 = (const float4*)(feaT + ((long)b * NN + idx) * 64);
#pragma unroll
        for (int k = 0; k < 8; k++) {
            *(float4*)&sm[base + g * 68 + half * 32 + k * 4] = f4[half * 8 + k];
        }
    }
    __syncthreads();

    float m0 = -1e30f, m1 = -1e30f;
#pragma unroll 2
    for (int g = 0; g < GG; g++) {
        float a0 = 0.f, a1 = 0.f;
#pragma unroll
        for (int c4 = 0; c4 < 17; c4++) {
            float4 gv = *(float4*)&sm[base + g * 68 + c4 * 4];
            a0 = fmaf(gv.x, wa[4 * c4 + 0], a0);
            a0 = fmaf(gv.y, wa[4 * c4 + 1], a0);
            a0 = fmaf(gv.z, wa[4 * c4 + 2], a0);
            a0 = fmaf(gv.w, wa[4 * c4 + 3], a0);
            a1 = fmaf(gv.x, wb[4 * c4 + 0], a1);
            a1 = fmaf(gv.y, wb[4 * c4 + 1], a1);
            a1 = fmaf(gv.z, wb[4 * c4 + 2], a1);
            a1 = fmaf(gv.w, wb[4 * c4 + 3], a1);
        }
        m0 = fmaxf(m0, a0);
        m1 = fmaxf(m1, a1);
    }
    // outputs: (B,3,S) then (B,128,S); relu(max) == max(relu)
    out[49152 + ((long)b * 128 + l) * SS + s]      = fmaxf(m0, 0.f);
    out[49152 + ((long)b * 128 + l + 64) * SS + s] = fmaxf(m1, 0.f);
}

// ---------------------------------------------------------------------------
extern "C" void kernel_launch(void* const* d_in, const int* in_sizes, int n_in,
                              void* d_out, int out_size, void* d_ws, size_t ws_size,
                              hipStream_t stream) {
    const float* coor = (const float*)d_in[0];   // (16,3,8192)
    const float* fea  = (const float*)d_in[1];   // (16,64,8192)
    const float* Wm   = (const float*)d_in[2];   // (128,67)
    float* out = (float*)d_out;

    char* ws = (char*)d_ws;
    float4* pts4 = (float4*)ws;                               //  2 MB
    float*  feaT = (float*)(ws + 2097152);                    // 32 MB
    float4* qpts = (float4*)(ws + 2097152 + 33554432);        // 256 KB
    int*    gidx = (int*)(ws + 2097152 + 33554432 + 262144);  //  2 MB

    k_pts<<<(BB * NN) / 256, 256, 0, stream>>>(coor, pts4);
    k_tr<<<dim3(NN / 64, BB), 256, 0, stream>>>(fea, feaT);
    k_fps<<<BB, 512, 0, stream>>>(pts4, qpts, out);
    k_knn<<<BB * SS, 64, 0, stream>>>(pts4, qpts, gidx);
    k_mlp<<<(BB * SS) / 4, 256, 0, stream>>>(pts4, feaT, qpts, gidx, Wm, out);
}